// Round 6
// baseline (250.901 us; speedup 1.0000x reference)
//
#include <hip/hip_runtime.h>
#include <math.h>

typedef __bf16 bf16x8 __attribute__((ext_vector_type(8)));
typedef float f32x4 __attribute__((ext_vector_type(4)));

// ---------- helpers ----------

__device__ __forceinline__ unsigned short f2bf(float f) {
    unsigned int u = __float_as_uint(f);
    u += 0x7FFFu + ((u >> 16) & 1u);   // round-to-nearest-even
    return (unsigned short)(u >> 16);
}

// fast logcosh via HW v_exp/v_log (TRANS pipe). abs err ~1e-6/elem, budget 0.02.
__device__ __forceinline__ float logcosh_fast(float v) {
    float a = fabsf(v);
    float t = __expf(-2.0f * a);
    return a + (__logf(1.0f + t) - 0.6931471805599453f);
}

// DPP row_shr add; after shr 1,2,4,8 lane 15 of each 16-lane row holds row sum.
template <int CTRL>
__device__ __forceinline__ float dppadd(float x) {
    int y = __builtin_amdgcn_update_dpp(0, __float_as_int(x), CTRL, 0xf, 0xf, true);
    return x + __int_as_float(y);
}

__device__ __forceinline__ void gload_lds16(const void* g, void* l) {
    __builtin_amdgcn_global_load_lds(
        (__attribute__((address_space(1))) void*)(void*)g,
        (__attribute__((address_space(3))) void*)l, 16, 0, 0);
}

#define SBAR()  __builtin_amdgcn_s_barrier()
#define SCHED() __builtin_amdgcn_sched_barrier(0)

// ---------- kernel 1: invert permutations ----------
__global__ __launch_bounds__(256) void k_invert(const int* __restrict__ perms,
                                                int* __restrict__ inv) {
    int t = blockIdx.x * 256 + threadIdx.x;
    int g = t >> 10, n = t & 1023;
    inv[(g << 10) + perms[t]] = n;
}

// ---------- kernel 2: bT[j][k] = bf16(W[inv[g][k]][f]), j = g*16+f ----------
__global__ __launch_bounds__(256) void k_build_bt(const float* __restrict__ W,
                                                  const int* __restrict__ inv,
                                                  unsigned short* __restrict__ bT) {
    int j = blockIdx.x;
    int g = j >> 4, f = j & 15;
    const int* invg = inv + (g << 10);
    size_t rowbase = (size_t)j << 10;
#pragma unroll
    for (int i = 0; i < 4; ++i) {
        int k = (i << 8) + threadIdx.x;
        int n = invg[k];
        bT[rowbase + k] = f2bf(W[(n << 4) + f]);
    }
}

// ---------- kernel 3: x -> bf16, out[row] = v_bias * sum(x[row]) ----------
__global__ __launch_bounds__(256) void k_convert(const float* __restrict__ x,
                                                 const float* __restrict__ vb,
                                                 unsigned short* __restrict__ xb,
                                                 float* __restrict__ out) {
    int row = blockIdx.x, tid = threadIdx.x;
    size_t base = ((size_t)row << 10) + (tid << 2);
    float4 v = *reinterpret_cast<const float4*>(x + base);
    ushort4 h;
    h.x = f2bf(v.x); h.y = f2bf(v.y); h.z = f2bf(v.z); h.w = f2bf(v.w);
    *reinterpret_cast<ushort4*>(xb + base) = h;
    float s = v.x + v.y + v.z + v.w;
#pragma unroll
    for (int off = 32; off > 0; off >>= 1) s += __shfl_down(s, off);
    __shared__ float ls[4];
    if ((tid & 63) == 0) ls[tid >> 6] = s;
    __syncthreads();
    if (tid == 0) out[row] = vb[0] * (ls[0] + ls[1] + ls[2] + ls[3]);
}

// ---------- kernel 4: 256x256 GEMM, quad-pipelined schedule + fused logcosh ------
// Per K-tile 4 phases; phase p issues ds_reads for quad p+1 and waits a COUNTED
// lgkm for quad p's reads (issued last phase) -> MFMA overlaps read completion.
//   P0: read aF[4-7](8); stage (t+1).Bh0; SBAR; lgkm(8);  q00
//   P1: read bF[2-3](4); stage (t+1).Bh1; SBAR; lgkm(4);  q10
//   P2:                  stage (t+2).Ah0; SBAR; lgkm(0);  q01; vmcnt(2)
//   P3: read next q00(12) from other buf; stage (t+2).Ah1; SBAR; q11
// WAR safety: A-reads of tile t collectively drained at P1-end barrier (before
// P2/P3 stages into As[p]); B-reads at P2's lgkm(0)+SBAR (before t+1.P0 stage
// into Bs[p]). RAW: vmcnt(2) at t.P2 guarantees tile t+1 fully landed before
// t.P3 reads it (tail: vmcnt(0) at t=14).

#define MFMA_QUAD(MH, NH)                                                        \
    _Pragma("unroll") for (int m_ = 0; m_ < 4; ++m_)                             \
    _Pragma("unroll") for (int n_ = 0; n_ < 2; ++n_)                             \
    _Pragma("unroll") for (int kk_ = 0; kk_ < 2; ++kk_)                          \
        acc[(MH) * 4 + m_][(NH) * 2 + n_] =                                      \
            __builtin_amdgcn_mfma_f32_16x16x32_bf16(                             \
                aF[(MH) * 4 + m_][kk_], bF[(NH) * 2 + n_][kk_],                  \
                acc[(MH) * 4 + m_][(NH) * 2 + n_], 0, 0, 0);

// stage one half-tile (128 rows x 64 cols bf16 = 16KB) = 2 gload_lds x 512 thr
__device__ __forceinline__ void stage_half(unsigned short* dst,
                                           const unsigned short* src, int h,
                                           int tid, int wv) {
#pragma unroll
    for (int j = 0; j < 2; ++j) {
        int c0 = (h * 128 + j * 64) * 8;       // base chunk of this instr
        int cc = c0 + tid;                     // this thread's 16B chunk
        int r = cc >> 3;                       // tile row 0..255
        int cs = (cc & 7) ^ (r & 7);           // pre-swizzled source octet
        gload_lds16(src + (((size_t)r) << 10) + (cs << 3),
                    dst + ((c0 + wv * 64) << 3));
    }
}

template <int VM, bool STB, bool STA, bool RDN>
__device__ __forceinline__ void tile4(
    const unsigned short* Ap, const unsigned short* Bp,   // current read buffers
    unsigned short* BsQ, unsigned short* AsP,             // stage dests
    const unsigned short* bsrc, const unsigned short* xsrc,
    const unsigned short* Aq, const unsigned short* Bq,   // next-tile read bufs
    bf16x8 (&aF)[8][2], bf16x8 (&bF)[4][2], f32x4 (&acc)[8][4],
    int aRow, int bRow, int po0, int po1, int tid, int wv) {
    // ---- P0: reads for q10; MFMA q00
#pragma unroll
    for (int m = 4; m < 8; ++m) {
        aF[m][0] = *reinterpret_cast<const bf16x8*>(Ap + aRow + po0 + m * 1024);
        aF[m][1] = *reinterpret_cast<const bf16x8*>(Ap + aRow + po1 + m * 1024);
    }
    if (STB) stage_half(BsQ, bsrc, 0, tid, wv);
    SCHED(); SBAR();
    asm volatile("s_waitcnt lgkmcnt(8)" ::: "memory");   // q00's 12 reads done
    SCHED();
    __builtin_amdgcn_s_setprio(1);
    MFMA_QUAD(0, 0)
    __builtin_amdgcn_s_setprio(0);
    SCHED(); SBAR();

    // ---- P1: reads for q01; MFMA q10
#pragma unroll
    for (int n = 2; n < 4; ++n) {
        bF[n][0] = *reinterpret_cast<const bf16x8*>(Bp + bRow + po0 + n * 1024);
        bF[n][1] = *reinterpret_cast<const bf16x8*>(Bp + bRow + po1 + n * 1024);
    }
    if (STB) stage_half(BsQ, bsrc, 1, tid, wv);
    SCHED(); SBAR();
    asm volatile("s_waitcnt lgkmcnt(4)" ::: "memory");   // q10's 8 reads done
    SCHED();
    __builtin_amdgcn_s_setprio(1);
    MFMA_QUAD(1, 0)
    __builtin_amdgcn_s_setprio(0);
    SCHED(); SBAR();

    // ---- P2: MFMA q01; counted vmcnt (tile t+1 landed)
    if (STA) stage_half(AsP, xsrc, 0, tid, wv);
    SCHED(); SBAR();
    asm volatile("s_waitcnt lgkmcnt(0)" ::: "memory");   // q01's 4 reads done
    SCHED();
    __builtin_amdgcn_s_setprio(1);
    MFMA_QUAD(0, 1)
    __builtin_amdgcn_s_setprio(0);
    SCHED();
    if (VM == 2)      { asm volatile("s_waitcnt vmcnt(2)" ::: "memory"); }
    else if (VM == 0) { asm volatile("s_waitcnt vmcnt(0)" ::: "memory"); }
    SCHED(); SBAR();

    // ---- P3: reads for NEXT tile's q00 (other buffer); MFMA q11
    if (RDN) {
#pragma unroll
        for (int m = 0; m < 4; ++m) {
            aF[m][0] = *reinterpret_cast<const bf16x8*>(Aq + aRow + po0 + m * 1024);
            aF[m][1] = *reinterpret_cast<const bf16x8*>(Aq + aRow + po1 + m * 1024);
        }
#pragma unroll
        for (int n = 0; n < 2; ++n) {
            bF[n][0] = *reinterpret_cast<const bf16x8*>(Bq + bRow + po0 + n * 1024);
            bF[n][1] = *reinterpret_cast<const bf16x8*>(Bq + bRow + po1 + n * 1024);
        }
    }
    if (STA) stage_half(AsP, xsrc, 1, tid, wv);
    SCHED(); SBAR();
    __builtin_amdgcn_s_setprio(1);
    MFMA_QUAD(1, 1)
    __builtin_amdgcn_s_setprio(0);
    SCHED(); SBAR();
}

__global__ __launch_bounds__(512, 2) void k_gemm(const unsigned short* __restrict__ xb,
                                                 const unsigned short* __restrict__ bT,
                                                 const float* __restrict__ bias,
                                                 float* __restrict__ partial, int B) {
    __shared__ unsigned short As[2][256 * 64];
    __shared__ unsigned short Bs[2][256 * 64];

    const int tid = threadIdx.x;
    const int lane = tid & 63;
    const int wv = tid >> 6;           // 0..7
    const int wm = wv >> 2;            // 0..1  (M half)
    const int wn = wv & 3;             // 0..3  (N quarter)
    const int lr = lane & 15;
    const int lk = lane >> 4;

    // XCD-bijective swizzle (nwg = 1024, % 8 == 0)
    const int fid = blockIdx.y * gridDim.x + blockIdx.x;
    const int cpx = (gridDim.x * gridDim.y) >> 3;
    const int swz = (fid & 7) * cpx + (fid >> 3);
    const int cbx = swz & 15;          // col block (0..15)
    const int row0 = (swz >> 4) << 8;  // row block * 256
    const int j0 = cbx << 8;

    const unsigned short* xbase = xb + ((size_t)row0 << 10);
    const unsigned short* bbase = bT + ((size_t)j0 << 10);

    // hoisted per-wave LDS read bases (short units); +m*1024 imm offsets
    const int aRow = (wm * 128 + lr) * 64;
    const int bRow = (wn * 64 + lr) * 64;
    const int po0 = (lk ^ (lr & 7)) * 8;
    const int po1 = ((4 + lk) ^ (lr & 7)) * 8;

    f32x4 acc[8][4];
#pragma unroll
    for (int m = 0; m < 8; ++m)
#pragma unroll
        for (int n = 0; n < 4; ++n)
            acc[m][n] = {0.f, 0.f, 0.f, 0.f};

    bf16x8 aF[8][2], bF[4][2];

    // ---- prologue: tile0 (4 halves) + tile1 (A halves); then tile0 q00 reads ----
    stage_half(&As[0][0], xbase, 0, tid, wv);
    stage_half(&As[0][0], xbase, 1, tid, wv);
    stage_half(&Bs[0][0], bbase, 0, tid, wv);
    stage_half(&Bs[0][0], bbase, 1, tid, wv);
    stage_half(&As[1][0], xbase + 64, 0, tid, wv);
    stage_half(&As[1][0], xbase + 64, 1, tid, wv);
    asm volatile("s_waitcnt vmcnt(4)" ::: "memory");   // tile0 fully landed
    SCHED(); SBAR();
#pragma unroll
    for (int m = 0; m < 4; ++m) {
        aF[m][0] = *reinterpret_cast<const bf16x8*>(&As[0][0] + aRow + po0 + m * 1024);
        aF[m][1] = *reinterpret_cast<const bf16x8*>(&As[0][0] + aRow + po1 + m * 1024);
    }
#pragma unroll
    for (int n = 0; n < 2; ++n) {
        bF[n][0] = *reinterpret_cast<const bf16x8*>(&Bs[0][0] + bRow + po0 + n * 1024);
        bF[n][1] = *reinterpret_cast<const bf16x8*>(&Bs[0][0] + bRow + po1 + n * 1024);
    }
    SCHED();

    // ---- main loop: tiles 0..13, guard-free ----
    for (int tt = 0; tt < 7; ++tt) {
        const int t0 = tt * 2;
        tile4<2, true, true, true>(&As[0][0], &Bs[0][0], &Bs[1][0], &As[0][0],
                                   bbase + ((t0 + 1) << 6), xbase + ((t0 + 2) << 6),
                                   &As[1][0], &Bs[1][0],
                                   aF, bF, acc, aRow, bRow, po0, po1, tid, wv);
        tile4<2, true, true, true>(&As[1][0], &Bs[1][0], &Bs[0][0], &As[1][0],
                                   bbase + ((t0 + 2) << 6), xbase + ((t0 + 3) << 6),
                                   &As[0][0], &Bs[0][0],
                                   aF, bF, acc, aRow, bRow, po0, po1, tid, wv);
    }
    // ---- tail: tile14 (stage t15 B halves only; vmcnt(0)), tile15 (no stages) ----
    tile4<0, true, false, true>(&As[0][0], &Bs[0][0], &Bs[1][0], &As[0][0],
                                bbase + (15 << 6), xbase,
                                &As[1][0], &Bs[1][0],
                                aF, bF, acc, aRow, bRow, po0, po1, tid, wv);
    tile4<-1, false, false, false>(&As[1][0], &Bs[1][0], &Bs[0][0], &As[1][0],
                                   bbase, xbase,
                                   &As[0][0], &Bs[0][0],
                                   aF, bF, acc, aRow, bRow, po0, po1, tid, wv);

    // ---- epilogue: fast logcosh + DPP row-reduce; reuse As as scratch ----
    float* rowsum = (float*)&As[0][0];   // [4][256]
    const float bv = bias[lr];           // C col % 16 == lane&15
#pragma unroll
    for (int m = 0; m < 8; ++m) {
#pragma unroll
        for (int r = 0; r < 4; ++r) {
            float s = 0.f;
#pragma unroll
            for (int n = 0; n < 4; ++n) s += logcosh_fast(acc[m][n][r] + bv);
            s = dppadd<0x111>(s);
            s = dppadd<0x112>(s);
            s = dppadd<0x114>(s);
            s = dppadd<0x118>(s);
            if (lr == 15)
                rowsum[wn * 256 + wm * 128 + m * 16 + lk * 4 + r] = s;
        }
    }
    __syncthreads();
    if (tid < 256) {
        float s = rowsum[tid] + rowsum[256 + tid] + rowsum[512 + tid] + rowsum[768 + tid];
        partial[(size_t)cbx * B + row0 + tid] = s;
    }
}

// ---------- kernel 5: out[b] += sum_cb partial[cb][b] ----------
__global__ __launch_bounds__(256) void k_final(const float* __restrict__ partial,
                                               float* __restrict__ out, int ncb, int B) {
    int b = blockIdx.x * 256 + threadIdx.x;
    float s = out[b];
    for (int c = 0; c < ncb; ++c) s += partial[(size_t)c * B + b];
    out[b] = s;
}

// ---------- launch ----------
extern "C" void kernel_launch(void* const* d_in, const int* in_sizes, int n_in,
                              void* d_out, int out_size, void* d_ws, size_t ws_size,
                              hipStream_t stream) {
    const float* x      = (const float*)d_in[0];  // [B,1024]
    const float* W      = (const float*)d_in[1];  // [1024,16]
    const float* bias   = (const float*)d_in[2];  // [16]
    const float* v_bias = (const float*)d_in[3];  // [1]
    const int*   perms  = (const int*)d_in[4];    // [G,1024]
    float* out = (float*)d_out;

    const int N  = 1024;
    const int B  = in_sizes[0] / N;   // 16384
    const int G  = in_sizes[4] / N;   // 256
    const int GF = G * 16;            // 4096
    const int NCB = GF / 256;         // 16 col blocks

    char* w = (char*)d_ws;
    unsigned short* xb = (unsigned short*)w;                           // B*N*2   = 32 MB
    unsigned short* bT = (unsigned short*)(w + (size_t)B * N * 2);     // GF*N*2  = 8 MB
    int* inv = (int*)(w + (size_t)B * N * 2 + (size_t)GF * N * 2);     // G*N*4   = 1 MB
    float* partial = (float*)(w + (size_t)B * N * 2 + (size_t)GF * N * 2
                              + (size_t)G * N * 4);                    // NCB*B*4 = 1 MB

    k_invert<<<G * N / 256, 256, 0, stream>>>(perms, inv);
    k_build_bt<<<GF, 256, 0, stream>>>(W, inv, bT);
    k_convert<<<B, 256, 0, stream>>>(x, v_bias, xb, out);
    k_gemm<<<dim3(NCB, B / 256), 512, 0, stream>>>(xb, bT, bias, partial, B);
    k_final<<<B / 256, 256, 0, stream>>>(partial, out, NCB, B);
}

// Round 7
// 188.417 us; speedup vs baseline: 1.3316x; 1.3316x over previous
//
#include <hip/hip_runtime.h>
#include <math.h>

typedef __bf16 bf16x8 __attribute__((ext_vector_type(8)));
typedef float f32x4 __attribute__((ext_vector_type(4)));

// ---------- helpers ----------

__device__ __forceinline__ unsigned short f2bf(float f) {
    unsigned int u = __float_as_uint(f);
    u += 0x7FFFu + ((u >> 16) & 1u);   // round-to-nearest-even
    return (unsigned short)(u >> 16);
}

// fast logcosh via HW v_exp/v_log (TRANS pipe). abs err ~1e-6/elem, budget 0.02.
__device__ __forceinline__ float logcosh_fast(float v) {
    float a = fabsf(v);
    float t = __expf(-2.0f * a);
    return a + (__logf(1.0f + t) - 0.6931471805599453f);
}

// DPP row_shr add; after shr 1,2,4,8 lane 15 of each 16-lane row holds row sum.
template <int CTRL>
__device__ __forceinline__ float dppadd(float x) {
    int y = __builtin_amdgcn_update_dpp(0, __float_as_int(x), CTRL, 0xf, 0xf, true);
    return x + __int_as_float(y);
}

__device__ __forceinline__ void gload_lds16(const void* g, void* l) {
    __builtin_amdgcn_global_load_lds(
        (__attribute__((address_space(1))) void*)(void*)g,
        (__attribute__((address_space(3))) void*)l, 16, 0, 0);
}

#define SBAR()  __builtin_amdgcn_s_barrier()
#define SCHED() __builtin_amdgcn_sched_barrier(0)

// ---------- kernel 1: invert permutations ----------
__global__ __launch_bounds__(256) void k_invert(const int* __restrict__ perms,
                                                int* __restrict__ inv) {
    int t = blockIdx.x * 256 + threadIdx.x;
    int g = t >> 10, n = t & 1023;
    inv[(g << 10) + perms[t]] = n;
}

// ---------- kernel 2: bT[j][k] = bf16(W[inv[g][k]][f]), j = g*16+f ----------
__global__ __launch_bounds__(256) void k_build_bt(const float* __restrict__ W,
                                                  const int* __restrict__ inv,
                                                  unsigned short* __restrict__ bT) {
    int j = blockIdx.x;
    int g = j >> 4, f = j & 15;
    const int* invg = inv + (g << 10);
    size_t rowbase = (size_t)j << 10;
#pragma unroll
    for (int i = 0; i < 4; ++i) {
        int k = (i << 8) + threadIdx.x;
        int n = invg[k];
        bT[rowbase + k] = f2bf(W[(n << 4) + f]);
    }
}

// ---------- kernel 3: x -> bf16, out[row] = v_bias * sum(x[row]) ----------
__global__ __launch_bounds__(256) void k_convert(const float* __restrict__ x,
                                                 const float* __restrict__ vb,
                                                 unsigned short* __restrict__ xb,
                                                 float* __restrict__ out) {
    int row = blockIdx.x, tid = threadIdx.x;
    size_t base = ((size_t)row << 10) + (tid << 2);
    float4 v = *reinterpret_cast<const float4*>(x + base);
    ushort4 h;
    h.x = f2bf(v.x); h.y = f2bf(v.y); h.z = f2bf(v.z); h.w = f2bf(v.w);
    *reinterpret_cast<ushort4*>(xb + base) = h;
    float s = v.x + v.y + v.z + v.w;
#pragma unroll
    for (int off = 32; off > 0; off >>= 1) s += __shfl_down(s, off);
    __shared__ float ls[4];
    if ((tid & 63) == 0) ls[tid >> 6] = s;
    __syncthreads();
    if (tid == 0) out[row] = vb[0] * (ls[0] + ls[1] + ls[2] + ls[3]);
}

// ---------- kernel 4: 256x256 GEMM, m-walk 1:1 interleave + fused logcosh -------
// Per K-tile (BK=64, dbuf LDS, 8 waves 2m x 4n, per-wave 128x64):
//   tile start: read bF[0..3][0..1] (8) + aF[0],aF[1] (4)
//   phases m=0..5: { read aF[m+2] (2); lgkm(4) -> aF[m] done; 8 MFMA acc[m][*] }
//   lgkm(0); SBAR  (all waves' reads of buf p complete)
//   phase 6: stage A(t+2) -> buf p (4 instr); 8 MFMA m=6   (regs only)
//   phase 7: stage B(t+2) -> buf p (4 instr); 8 MFMA m=7; vmcnt(8); SBAR
// vmcnt(8): outstanding = t+2's 8 (just issued) [+ t+1's, older] -> t+1 landed.
// Live frags <= bF(8) + aF window(6) -> no spills (acc 128 AGPR + ~90 VGPR < 256).

#define MFMA_M(MM)                                                               \
    _Pragma("unroll") for (int k_ = 0; k_ < 2; ++k_)                             \
    _Pragma("unroll") for (int n_ = 0; n_ < 4; ++n_)                             \
        acc[MM][n_] = __builtin_amdgcn_mfma_f32_16x16x32_bf16(                   \
            aF[MM][k_], bF[n_][k_], acc[MM][n_], 0, 0, 0);

// stage one half-tile (128 rows x 64 cols bf16 = 16KB) = 2 gload_lds x 512 thr
__device__ __forceinline__ void stage_half(unsigned short* dst,
                                           const unsigned short* src, int h,
                                           int tid, int wv) {
#pragma unroll
    for (int j = 0; j < 2; ++j) {
        int c0 = (h * 128 + j * 64) * 8;       // base chunk of this instr
        int cc = c0 + tid;                     // this thread's 16B chunk
        int r = cc >> 3;                       // tile row 0..255
        int cs = (cc & 7) ^ (r & 7);           // pre-swizzled source octet
        gload_lds16(src + (((size_t)r) << 10) + (cs << 3),
                    dst + ((c0 + wv * 64) << 3));
    }
}

template <bool STAGE, int VM>
__device__ __forceinline__ void tile_iter(
    const unsigned short* Ap, const unsigned short* Bp,   // read buffers (= stage dst)
    unsigned short* AsD, unsigned short* BsD,
    const unsigned short* xsrc, const unsigned short* bsrc,   // t+2 global srcs
    f32x4 (&acc)[8][4], int aRow, int bRow, int po0, int po1, int tid, int wv) {
    bf16x8 aF[8][2], bF[4][2];

    // tile start: 8 bF reads then 4 aF reads (issue order = ledger order)
#pragma unroll
    for (int n = 0; n < 4; ++n) {
        bF[n][0] = *reinterpret_cast<const bf16x8*>(Bp + bRow + po0 + n * 1024);
        bF[n][1] = *reinterpret_cast<const bf16x8*>(Bp + bRow + po1 + n * 1024);
    }
#pragma unroll
    for (int m = 0; m < 2; ++m) {
        aF[m][0] = *reinterpret_cast<const bf16x8*>(Ap + aRow + po0 + m * 1024);
        aF[m][1] = *reinterpret_cast<const bf16x8*>(Ap + aRow + po1 + m * 1024);
    }
    SCHED();

    // phases 0..5: read ahead 2 frags, wait lgkm(4) (aF[m] done), 8 MFMA
#pragma unroll
    for (int m = 0; m < 6; ++m) {
        aF[m + 2][0] = *reinterpret_cast<const bf16x8*>(Ap + aRow + po0 + (m + 2) * 1024);
        aF[m + 2][1] = *reinterpret_cast<const bf16x8*>(Ap + aRow + po1 + (m + 2) * 1024);
        SCHED();
        asm volatile("s_waitcnt lgkmcnt(4)" ::: "memory");
        SCHED();
        __builtin_amdgcn_s_setprio(1);
        MFMA_M(m)
        __builtin_amdgcn_s_setprio(0);
        SCHED();
    }

    // all 24 reads of this buffer complete in every wave -> stages into it are safe
    asm volatile("s_waitcnt lgkmcnt(0)" ::: "memory");
    SCHED();
    SBAR();

    // phase 6: stage A(t+2); MFMA m=6 (register-only)
    if (STAGE) { stage_half(AsD, xsrc, 0, tid, wv); stage_half(AsD, xsrc, 1, tid, wv); }
    SCHED();
    __builtin_amdgcn_s_setprio(1);
    MFMA_M(6)
    __builtin_amdgcn_s_setprio(0);
    SCHED();

    // phase 7: stage B(t+2); MFMA m=7; counted vmcnt; barrier
    if (STAGE) { stage_half(BsD, bsrc, 0, tid, wv); stage_half(BsD, bsrc, 1, tid, wv); }
    SCHED();
    __builtin_amdgcn_s_setprio(1);
    MFMA_M(7)
    __builtin_amdgcn_s_setprio(0);
    SCHED();
    if (VM == 8)      { asm volatile("s_waitcnt vmcnt(8)" ::: "memory"); }
    else if (VM == 0) { asm volatile("s_waitcnt vmcnt(0)" ::: "memory"); }
    SCHED();
    SBAR();
}

__global__ __launch_bounds__(512, 2) void k_gemm(const unsigned short* __restrict__ xb,
                                                 const unsigned short* __restrict__ bT,
                                                 const float* __restrict__ bias,
                                                 float* __restrict__ partial, int B) {
    __shared__ unsigned short As[2][256 * 64];
    __shared__ unsigned short Bs[2][256 * 64];

    const int tid = threadIdx.x;
    const int lane = tid & 63;
    const int wv = tid >> 6;           // 0..7
    const int wm = wv >> 2;            // 0..1  (M half)
    const int wn = wv & 3;             // 0..3  (N quarter)
    const int lr = lane & 15;
    const int lk = lane >> 4;

    // XCD-bijective swizzle (nwg = 1024, % 8 == 0)
    const int fid = blockIdx.y * gridDim.x + blockIdx.x;
    const int cpx = (gridDim.x * gridDim.y) >> 3;
    const int swz = (fid & 7) * cpx + (fid >> 3);
    const int cbx = swz & 15;          // col block (0..15)
    const int row0 = (swz >> 4) << 8;  // row block * 256
    const int j0 = cbx << 8;

    const unsigned short* xbase = xb + ((size_t)row0 << 10);
    const unsigned short* bbase = bT + ((size_t)j0 << 10);

    // hoisted per-wave LDS read bases (short units); +m*1024 imm offsets
    const int aRow = (wm * 128 + lr) * 64;
    const int bRow = (wn * 64 + lr) * 64;
    const int po0 = (lk ^ (lr & 7)) * 8;
    const int po1 = ((4 + lk) ^ (lr & 7)) * 8;

    f32x4 acc[8][4];
#pragma unroll
    for (int m = 0; m < 8; ++m)
#pragma unroll
        for (int n = 0; n < 4; ++n)
            acc[m][n] = {0.f, 0.f, 0.f, 0.f};

    // ---- prologue: stage tile0 (8 instr) + tile1 (8 instr); wait tile0 ----
    stage_half(&As[0][0], xbase, 0, tid, wv);
    stage_half(&As[0][0], xbase, 1, tid, wv);
    stage_half(&Bs[0][0], bbase, 0, tid, wv);
    stage_half(&Bs[0][0], bbase, 1, tid, wv);
    stage_half(&As[1][0], xbase + 64, 0, tid, wv);
    stage_half(&As[1][0], xbase + 64, 1, tid, wv);
    stage_half(&Bs[1][0], bbase + 64, 0, tid, wv);
    stage_half(&Bs[1][0], bbase + 64, 1, tid, wv);
    asm volatile("s_waitcnt vmcnt(8)" ::: "memory");   // tile0 landed
    SCHED();
    SBAR();

    // ---- main loop: tiles 0..13 steady (stage t+2, vmcnt(8)), 14-15 tail ----
    for (int tt = 0; tt < 7; ++tt) {
        const int t0 = tt * 2;
        tile_iter<true, 8>(&As[0][0], &Bs[0][0], &As[0][0], &Bs[0][0],
                           xbase + ((t0 + 2) << 6), bbase + ((t0 + 2) << 6),
                           acc, aRow, bRow, po0, po1, tid, wv);
        tile_iter<true, 8>(&As[1][0], &Bs[1][0], &As[1][0], &Bs[1][0],
                           xbase + ((t0 + 3) << 6), bbase + ((t0 + 3) << 6),
                           acc, aRow, bRow, po0, po1, tid, wv);
    }
    tile_iter<false, 0>(&As[0][0], &Bs[0][0], &As[0][0], &Bs[0][0],
                        xbase, bbase, acc, aRow, bRow, po0, po1, tid, wv);
    tile_iter<false, -1>(&As[1][0], &Bs[1][0], &As[1][0], &Bs[1][0],
                         xbase, bbase, acc, aRow, bRow, po0, po1, tid, wv);

    // ---- epilogue: fast logcosh + DPP row-reduce; reuse As as scratch ----
    float* rowsum = (float*)&As[0][0];   // [4][256]
    const float bv = bias[lr];           // C col % 16 == lane&15
#pragma unroll
    for (int m = 0; m < 8; ++m) {
#pragma unroll
        for (int r = 0; r < 4; ++r) {
            float s = 0.f;
#pragma unroll
            for (int n = 0; n < 4; ++n) s += logcosh_fast(acc[m][n][r] + bv);
            s = dppadd<0x111>(s);
            s = dppadd<0x112>(s);
            s = dppadd<0x114>(s);
            s = dppadd<0x118>(s);
            if (lr == 15)
                rowsum[wn * 256 + wm * 128 + m * 16 + lk * 4 + r] = s;
        }
    }
    __syncthreads();
    if (tid < 256) {
        float s = rowsum[tid] + rowsum[256 + tid] + rowsum[512 + tid] + rowsum[768 + tid];
        partial[(size_t)cbx * B + row0 + tid] = s;
    }
}

// ---------- kernel 5: out[b] += sum_cb partial[cb][b] ----------
__global__ __launch_bounds__(256) void k_final(const float* __restrict__ partial,
                                               float* __restrict__ out, int ncb, int B) {
    int b = blockIdx.x * 256 + threadIdx.x;
    float s = out[b];
    for (int c = 0; c < ncb; ++c) s += partial[(size_t)c * B + b];
    out[b] = s;
}

// ---------- launch ----------
extern "C" void kernel_launch(void* const* d_in, const int* in_sizes, int n_in,
                              void* d_out, int out_size, void* d_ws, size_t ws_size,
                              hipStream_t stream) {
    const float* x      = (const float*)d_in[0];  // [B,1024]
    const float* W      = (const float*)d_in[1];  // [1024,16]
    const float* bias   = (const float*)d_in[2];  // [16]
    const float* v_bias = (const float*)d_in[3];  // [1]
    const int*   perms  = (const int*)d_in[4];    // [G,1024]
    float* out = (float*)d_out;

    const int N  = 1024;
    const int B  = in_sizes[0] / N;   // 16384
    const int G  = in_sizes[4] / N;   // 256
    const int GF = G * 16;            // 4096
    const int NCB = GF / 256;         // 16 col blocks

    char* w = (char*)d_ws;
    unsigned short* xb = (unsigned short*)w;                           // B*N*2   = 32 MB
    unsigned short* bT = (unsigned short*)(w + (size_t)B * N * 2);     // GF*N*2  = 8 MB
    int* inv = (int*)(w + (size_t)B * N * 2 + (size_t)GF * N * 2);     // G*N*4   = 1 MB
    float* partial = (float*)(w + (size_t)B * N * 2 + (size_t)GF * N * 2
                              + (size_t)G * N * 4);                    // NCB*B*4 = 1 MB

    k_invert<<<G * N / 256, 256, 0, stream>>>(perms, inv);
    k_build_bt<<<GF, 256, 0, stream>>>(W, inv, bT);
    k_convert<<<B, 256, 0, stream>>>(x, v_bias, xb, out);
    k_gemm<<<dim3(NCB, B / 256), 512, 0, stream>>>(xb, bT, bias, partial, B);
    k_final<<<B / 256, 256, 0, stream>>>(partial, out, NCB, B);
}